// Round 5
// baseline (274.578 us; speedup 1.0000x reference)
//
#include <hip/hip_runtime.h>

#define N_NODES 50000
#define N_EDGES 800000
#define N_GRAPHS 256
#define D_FEAT 96
#define HIDDEN 32

#define NB2 391       // bins: bin = dst >> 7 (128 nodes/bin), 49999>>7 = 390
#define CAPB2 3072    // per-bin capacity; mean 2046, sd ~45 -> 22-sigma margin
#define PB 128        // partition blocks
#define PCHUNK 6250   // 128 * 6250 = 800000 exactly
#define GWIN 8        // pooled-graph LDS window per 128-node bin

// ---------------------------------------------------------------------------
// Kernel A: fused edge-partition (blocks 0..PB-1) + y = x@W1 (remaining blocks).
// The two halves are independent -> they overlap on the chip instead of
// serializing as two dispatches.
__global__ void __launch_bounds__(256)
k_front(const float* __restrict__ x, const float* __restrict__ W1,
        float* __restrict__ y,
        const int* __restrict__ src, const int* __restrict__ dst,
        int* __restrict__ gcursor, unsigned int* __restrict__ binned) {
    int blk = blockIdx.x;
    int tid = threadIdx.x;
    if (blk < PB) {
        // ---- edge partition by dst>>7 ----
        __shared__ int hist[NB2];
        __shared__ int base[NB2];
        for (int i = tid; i < NB2; i += 256) hist[i] = 0;
        __syncthreads();

        int e0 = blk * PCHUNK, e1 = e0 + PCHUNK;
        for (int e = e0 + tid; e < e1; e += 256)
            atomicAdd(&hist[dst[e] >> 7], 1);
        __syncthreads();

        for (int i = tid; i < NB2; i += 256) {
            int c = hist[i];
            base[i] = c ? atomicAdd(&gcursor[i], c) : 0;  // gcursor zeroed by memset
            hist[i] = 0;                                   // reuse as intra-block cursor
        }
        __syncthreads();

        for (int e = e0 + tid; e < e1; e += 256) {
            int d = dst[e];
            int b = d >> 7;
            int pos = base[b] + atomicAdd(&hist[b], 1);
            if (pos < CAPB2)  // statistically never taken
                binned[(size_t)b * CAPB2 + pos] =
                    (unsigned)src[e] | ((unsigned)(d & 127) << 16);
        }
    } else {
        // ---- y = x @ W1 : 32 lanes per node, lane = hidden feature ----
        int gid = (blk - PB) * 256 + tid;     // 0 .. N_NODES*HIDDEN-1 exactly
        int node = gid >> 5;
        int f = gid & 31;
        const float* xr = x + (size_t)node * D_FEAT;
        float acc = 0.f;
#pragma unroll
        for (int k = 0; k < D_FEAT; ++k)
            acc = fmaf(xr[k], W1[k * HIDDEN + f], acc);
        y[gid] = acc;
    }
}

// ---------------------------------------------------------------------------
// Kernel B: per-bin counting-sort -> CSR in LDS, register gather, MLP via
// intra-group shuffles, windowed mean-pool; LAST block computes the output.
__global__ void __launch_bounds__(1024)
k_back(const unsigned int* __restrict__ binned, const int* __restrict__ gcursor,
       const float* __restrict__ y, const int* __restrict__ batch,
       const float* __restrict__ b1, const float* __restrict__ W2,
       const float* __restrict__ b2,
       const float* __restrict__ Wc, const float* __restrict__ bc,
       float* __restrict__ sums, float* __restrict__ counts,
       int* __restrict__ done, float* __restrict__ out) {
    __shared__ unsigned int cnt[128];
    __shared__ unsigned int offs[129];
    __shared__ unsigned int cur[128];
    __shared__ unsigned int list[CAPB2];     // 12 KB
    __shared__ float w2s[HIDDEN * HIDDEN];   // 4 KB
    __shared__ float accs[GWIN * HIDDEN];
    __shared__ float cntsl[GWIN];
    __shared__ int is_last;

    int tid = threadIdx.x;
    int bin = blockIdx.x;
    if (tid < 128) cnt[tid] = 0;
    for (int i = tid; i < HIDDEN * HIDDEN; i += 1024) w2s[i] = W2[i];
    if (tid < GWIN * HIDDEN) accs[tid] = 0.f;
    if (tid < GWIN) cntsl[tid] = 0.f;
    __syncthreads();

    int ecount = gcursor[bin];
    if (ecount > CAPB2) ecount = CAPB2;
    const unsigned int* eb = binned + (size_t)bin * CAPB2;

    // pass A: per-node degree histogram (native int LDS atomics)
    for (int e = tid; e < ecount; e += 1024)
        atomicAdd(&cnt[eb[e] >> 16], 1u);
    __syncthreads();

    // pass B: exclusive scan over 128 entries
    if (tid < 128) offs[tid + 1] = cnt[tid];
    if (tid == 0) offs[0] = 0;
    __syncthreads();
    for (int d = 1; d < 128; d <<= 1) {
        unsigned v = 0;
        if (tid < 128) { v = offs[tid + 1]; if (tid >= d) v += offs[tid + 1 - d]; }
        __syncthreads();
        if (tid < 128) offs[tid + 1] = v;
        __syncthreads();
    }
    if (tid < 128) cur[tid] = offs[tid];
    __syncthreads();

    // pass C: placement into per-node CSR lists
    for (int e = tid; e < ecount; e += 1024) {
        unsigned p = eb[e];
        unsigned pos = atomicAdd(&cur[p >> 16], 1u);
        list[pos] = p & 0xFFFFu;
    }
    __syncthreads();

    int node0 = bin << 7;
    int nn = N_NODES - node0; if (nn > 128) nn = 128;
    int g = tid >> 5;      // group 0..31 (two groups per wave64)
    int f = tid & 31;      // feature lane
    int gfirst = batch[node0];

    for (int ln = g * 4; ln < g * 4 + 4; ++ln) {
        if (ln >= nn) break;
        int node = node0 + ln;
        float acc = y[(size_t)node * HIDDEN + f];       // self term
        int j = offs[ln], jend = offs[ln + 1];
        for (; j + 4 <= jend; j += 4) {                 // 4 y-rows in flight
            unsigned s0 = list[j], s1 = list[j + 1], s2 = list[j + 2], s3 = list[j + 3];
            float a0 = y[(size_t)s0 * HIDDEN + f];
            float a1 = y[(size_t)s1 * HIDDEN + f];
            float a2 = y[(size_t)s2 * HIDDEN + f];
            float a3 = y[(size_t)s3 * HIDDEN + f];
            acc += (a0 + a1) + (a2 + a3);
        }
        for (; j < jend; ++j)
            acc += y[(size_t)list[j] * HIDDEN + f];

        float h1 = fmaxf(acc + b1[f], 0.f);
        float h2 = b2[f];
#pragma unroll
        for (int k = 0; k < HIDDEN; ++k)                // h1[k] via intra-group shuffle
            h2 = fmaf(__shfl(h1, k, 32), w2s[k * HIDDEN + f], h2);
        float h = fmaxf(h2, 0.f);

        int gr = batch[node];
        int b = gr - gfirst;
        if (b < GWIN) {
            atomicAdd(&accs[b * HIDDEN + f], h);        // ~128 LDS fp adds/block total
            if (f == 0) atomicAdd(&cntsl[b], 1.f);
        } else {
            atomicAdd(&sums[(size_t)gr * HIDDEN + f], h);
            if (f == 0) atomicAdd(&counts[gr], 1.f);
        }
    }
    __syncthreads();

    // flush window to global (device-scope atomics)
    for (int i = tid; i < GWIN * HIDDEN; i += 1024) {
        float v = accs[i];
        if (v != 0.f) atomicAdd(&sums[(size_t)gfirst * HIDDEN + i], v);
    }
    if (tid < GWIN) {
        float c = cntsl[tid];
        if (c != 0.f) atomicAdd(&counts[gfirst + tid], c);
    }
    __threadfence();       // each thread's atomics ordered before the done-add
    __syncthreads();

    if (tid == 0) is_last = (atomicAdd(done, 1) == NB2 - 1);
    __syncthreads();

    if (is_last && tid < N_GRAPHS * 2) {
        // all other blocks' sums-atomics happen-before via done counter.
        // read with atomicAdd(p, 0) -> coherent device-scope RMW (G16).
        int gr = tid >> 1, c = tid & 1;
        float cv = atomicAdd(&counts[gr], 0.f);
        float inv = 1.f / fmaxf(cv, 1.f);
        float o = bc[c];
#pragma unroll
        for (int k = 0; k < HIDDEN; ++k)
            o = fmaf(atomicAdd(&sums[(size_t)gr * HIDDEN + k], 0.f) * inv,
                     Wc[k * 2 + c], o);
        out[gr * 2 + c] = o;
    }
}

// ---------------------------------------------------------------------------
extern "C" void kernel_launch(void* const* d_in, const int* in_sizes, int n_in,
                              void* d_out, int out_size, void* d_ws, size_t ws_size,
                              hipStream_t stream) {
    const float* x     = (const float*)d_in[0];
    const int*   ei    = (const int*)d_in[1];   // [2, N_EDGES]: src row then dst row
    const int*   batch = (const int*)d_in[2];
    const float* W1    = (const float*)d_in[3];
    const float* b1    = (const float*)d_in[4];
    const float* W2    = (const float*)d_in[5];
    const float* b2    = (const float*)d_in[6];
    const float* Wc    = (const float*)d_in[7];
    const float* bc    = (const float*)d_in[8];
    float* out = (float*)d_out;

    // Workspace layout (byte offsets):
    //   0        gcursor  NB2 int (1564 B, pad 2048)
    //   2048     sums     8192 f  (32768 B)
    //   34816    counts   256 f   (1024 B)
    //   35840    done     1 int   (pad to 36864)
    //   36864    binned   NB2*CAPB2 u32 (4804608 B)
    //   4841472  y        1.6M f  (6400000 B)   -> total ~11.2 MB
    char* ws = (char*)d_ws;
    int*          gcursor = (int*)ws;
    float*        sums    = (float*)(ws + 2048);
    float*        counts  = (float*)(ws + 34816);
    int*          done    = (int*)(ws + 35840);
    unsigned int* binned  = (unsigned int*)(ws + 36864);
    float*        y       = (float*)(ws + 4841472);

    hipMemsetAsync(d_ws, 0, 36864, stream);   // gcursor + sums + counts + done

    k_front<<<PB + N_NODES * HIDDEN / 256, 256, 0, stream>>>(
        x, W1, y, ei, ei + N_EDGES, gcursor, binned);

    k_back<<<NB2, 1024, 0, stream>>>(binned, gcursor, y, batch,
                                     b1, W2, b2, Wc, bc,
                                     sums, counts, done, out);
}

// Round 6
// 156.913 us; speedup vs baseline: 1.7499x; 1.7499x over previous
//
#include <hip/hip_runtime.h>

#define N_NODES 50000
#define N_EDGES 800000
#define N_GRAPHS 256
#define D_FEAT 96
#define HIDDEN 32

#define NB 196        // bins: bin = dst >> 8 (256 nodes/bin), 49999>>8 = 195
#define CAPB 8192     // per-bin capacity in global binned[]; mean 4096, sd 64
#define PB 200        // partition blocks
#define PCHUNK 4000   // 200 * 4000 = 800000 exactly
#define GWIN 16       // pooled-graph LDS window per 256-node bin
#define LCAP 6144     // per-bin LDS edge-list capacity (mean 4096 + 32 sigma)

// ---------------------------------------------------------------------------
// Kernel A: fused edge-partition (blocks 0..PB-1) + y = x@W1 (remaining).
// Independent halves overlap on-chip instead of serializing as 2 dispatches.
__global__ void __launch_bounds__(256)
k_front(const float* __restrict__ x, const float* __restrict__ W1,
        float* __restrict__ y,
        const int* __restrict__ src, const int* __restrict__ dst,
        int* __restrict__ gcursor, unsigned int* __restrict__ binned) {
    int blk = blockIdx.x;
    int tid = threadIdx.x;
    if (blk < PB) {
        // ---- edge partition by dst>>8 ----
        __shared__ int hist[NB];
        __shared__ int base[NB];
        for (int i = tid; i < NB; i += 256) hist[i] = 0;
        __syncthreads();

        int e0 = blk * PCHUNK, e1 = e0 + PCHUNK;
        for (int e = e0 + tid; e < e1; e += 256)
            atomicAdd(&hist[dst[e] >> 8], 1);
        __syncthreads();

        for (int i = tid; i < NB; i += 256) {
            int c = hist[i];
            base[i] = c ? atomicAdd(&gcursor[i], c) : 0;  // gcursor zeroed by memset
            hist[i] = 0;                                   // reuse as intra-block cursor
        }
        __syncthreads();

        for (int e = e0 + tid; e < e1; e += 256) {
            int d = dst[e];
            int b = d >> 8;
            int pos = base[b] + atomicAdd(&hist[b], 1);
            if (pos < CAPB)  // statistically never taken
                binned[(size_t)b * CAPB + pos] =
                    (unsigned)src[e] | ((unsigned)(d & 255) << 16);
        }
    } else {
        // ---- y = x @ W1 : 32 lanes per node, lane = hidden feature ----
        int gid = (blk - PB) * 256 + tid;     // 0 .. N_NODES*HIDDEN-1 exactly
        int node = gid >> 5;
        int f = gid & 31;
        const float4* xr4 = (const float4*)(x + (size_t)node * D_FEAT);  // 384B-aligned
        float acc = 0.f;
#pragma unroll
        for (int k4 = 0; k4 < D_FEAT / 4; ++k4) {
            float4 xv = xr4[k4];
            acc = fmaf(xv.x, W1[(k4 * 4 + 0) * HIDDEN + f], acc);
            acc = fmaf(xv.y, W1[(k4 * 4 + 1) * HIDDEN + f], acc);
            acc = fmaf(xv.z, W1[(k4 * 4 + 2) * HIDDEN + f], acc);
            acc = fmaf(xv.w, W1[(k4 * 4 + 3) * HIDDEN + f], acc);
        }
        y[gid] = acc;
    }
}

// ---------------------------------------------------------------------------
// Kernel B: per-bin counting-sort -> CSR in LDS, register gather, MLP via
// intra-group shuffles, windowed mean-pool. One 1024-thr block per 256-node bin.
// (Round-4-proven structure; NO device fence, NO fused output tail.)
__global__ void __launch_bounds__(1024)
k_agg(const unsigned int* __restrict__ binned, const int* __restrict__ gcursor,
      const float* __restrict__ y, const int* __restrict__ batch,
      const float* __restrict__ b1, const float* __restrict__ W2,
      const float* __restrict__ b2,
      float* __restrict__ sums, float* __restrict__ counts) {
    __shared__ unsigned int cnt[256];
    __shared__ unsigned int offs[257];
    __shared__ unsigned int cur[256];
    __shared__ unsigned int list[LCAP];      // 24 KB
    __shared__ float w2s[HIDDEN * HIDDEN];   // 4 KB
    __shared__ float accs[GWIN * HIDDEN];    // 2 KB
    __shared__ float cntsl[GWIN];

    int tid = threadIdx.x;
    int bin = blockIdx.x;
    if (tid < 256) cnt[tid] = 0;
    for (int i = tid; i < HIDDEN * HIDDEN; i += 1024) w2s[i] = W2[i];
    if (tid < GWIN * HIDDEN) accs[tid] = 0.f;
    if (tid < GWIN) cntsl[tid] = 0.f;
    __syncthreads();

    int ecount = gcursor[bin];
    if (ecount > LCAP) ecount = LCAP;        // statistically never
    const unsigned int* eb = binned + (size_t)bin * CAPB;

    // pass A: per-node degree histogram (native int LDS atomics)
    for (int e = tid; e < ecount; e += 1024)
        atomicAdd(&cnt[eb[e] >> 16], 1u);
    __syncthreads();

    // pass B: exclusive scan -> offs[0..256]
    if (tid < 256) offs[tid + 1] = cnt[tid];
    if (tid == 0) offs[0] = 0;
    __syncthreads();
    for (int d = 1; d < 256; d <<= 1) {
        unsigned v = 0;
        if (tid < 256) { v = offs[tid + 1]; if (tid >= d) v += offs[tid + 1 - d]; }
        __syncthreads();
        if (tid < 256) offs[tid + 1] = v;
        __syncthreads();
    }
    if (tid < 256) cur[tid] = offs[tid];
    __syncthreads();

    // pass C: placement into per-node CSR lists
    for (int e = tid; e < ecount; e += 1024) {
        unsigned p = eb[e];
        unsigned pos = atomicAdd(&cur[p >> 16], 1u);
        list[pos] = p & 0xFFFFu;
    }
    __syncthreads();

    int node0 = bin << 8;
    int nn = N_NODES - node0; if (nn > 256) nn = 256;
    int g = tid >> 5;      // group 0..31 (two groups per wave64)
    int f = tid & 31;      // feature lane
    int gfirst = batch[node0];

    for (int ln = g * 8; ln < g * 8 + 8; ++ln) {
        if (ln >= nn) break;
        int node = node0 + ln;
        float acc = y[(size_t)node * HIDDEN + f];       // self term
        int j = offs[ln], jend = offs[ln + 1];
        for (; j + 8 <= jend; j += 8) {                 // 8 y-rows in flight
            unsigned s0 = list[j],     s1 = list[j + 1], s2 = list[j + 2], s3 = list[j + 3];
            unsigned s4 = list[j + 4], s5 = list[j + 5], s6 = list[j + 6], s7 = list[j + 7];
            float a0 = y[(size_t)s0 * HIDDEN + f];
            float a1 = y[(size_t)s1 * HIDDEN + f];
            float a2 = y[(size_t)s2 * HIDDEN + f];
            float a3 = y[(size_t)s3 * HIDDEN + f];
            float a4 = y[(size_t)s4 * HIDDEN + f];
            float a5 = y[(size_t)s5 * HIDDEN + f];
            float a6 = y[(size_t)s6 * HIDDEN + f];
            float a7 = y[(size_t)s7 * HIDDEN + f];
            acc += ((a0 + a1) + (a2 + a3)) + ((a4 + a5) + (a6 + a7));
        }
        for (; j + 4 <= jend; j += 4) {
            unsigned s0 = list[j], s1 = list[j + 1], s2 = list[j + 2], s3 = list[j + 3];
            float a0 = y[(size_t)s0 * HIDDEN + f];
            float a1 = y[(size_t)s1 * HIDDEN + f];
            float a2 = y[(size_t)s2 * HIDDEN + f];
            float a3 = y[(size_t)s3 * HIDDEN + f];
            acc += (a0 + a1) + (a2 + a3);
        }
        for (; j < jend; ++j)
            acc += y[(size_t)list[j] * HIDDEN + f];

        float h1 = fmaxf(acc + b1[f], 0.f);
        float h2 = b2[f];
#pragma unroll
        for (int k = 0; k < HIDDEN; ++k)                // h1[k] via intra-group shuffle
            h2 = fmaf(__shfl(h1, k, 32), w2s[k * HIDDEN + f], h2);
        float h = fmaxf(h2, 0.f);

        int gr = batch[node];
        int b = gr - gfirst;
        if (b < GWIN) {
            atomicAdd(&accs[b * HIDDEN + f], h);        // ~256 LDS fp adds/block total
            if (f == 0) atomicAdd(&cntsl[b], 1.f);
        } else {
            atomicAdd(&sums[(size_t)gr * HIDDEN + f], h);
            if (f == 0) atomicAdd(&counts[gr], 1.f);
        }
    }
    __syncthreads();

    for (int i = tid; i < GWIN * HIDDEN; i += 1024) {
        float v = accs[i];
        if (v != 0.f) atomicAdd(&sums[(size_t)gfirst * HIDDEN + i], v);
    }
    if (tid < GWIN) {
        float c = cntsl[tid];
        if (c != 0.f) atomicAdd(&counts[gfirst + tid], c);
    }
}

// ---------------------------------------------------------------------------
// Kernel C: out[g] = (sums[g]/max(counts[g],1)) @ Wc + bc
__global__ void k_out(const float* __restrict__ sums, const float* __restrict__ counts,
                      const float* __restrict__ Wc, const float* __restrict__ bc,
                      float* __restrict__ out) {
    int g = threadIdx.x;
    if (g >= N_GRAPHS) return;
    float inv = 1.f / fmaxf(counts[g], 1.f);
    float o0 = bc[0], o1 = bc[1];
#pragma unroll
    for (int k = 0; k < HIDDEN; ++k) {
        float p = sums[(size_t)g * HIDDEN + k] * inv;
        o0 = fmaf(p, Wc[k * 2 + 0], o0);
        o1 = fmaf(p, Wc[k * 2 + 1], o1);
    }
    out[g * 2 + 0] = o0;
    out[g * 2 + 1] = o1;
}

// ---------------------------------------------------------------------------
extern "C" void kernel_launch(void* const* d_in, const int* in_sizes, int n_in,
                              void* d_out, int out_size, void* d_ws, size_t ws_size,
                              hipStream_t stream) {
    const float* x     = (const float*)d_in[0];
    const int*   ei    = (const int*)d_in[1];   // [2, N_EDGES]: src row then dst row
    const int*   batch = (const int*)d_in[2];
    const float* W1    = (const float*)d_in[3];
    const float* b1    = (const float*)d_in[4];
    const float* W2    = (const float*)d_in[5];
    const float* b2    = (const float*)d_in[6];
    const float* Wc    = (const float*)d_in[7];
    const float* bc    = (const float*)d_in[8];
    float* out = (float*)d_out;

    // Workspace layout (byte offsets):
    //   0        gcursor  NB int  (pad to 1024 B)
    //   1024     sums     8192 f  (32768 B)
    //   33792    counts   256 f   (1024 B)          -> memset first 34816 B
    //   34816    binned   NB*CAPB u32 (6422528 B)
    //   6457344  y        1.6M f  (6400000 B)
    char* ws = (char*)d_ws;
    int*          gcursor = (int*)ws;
    float*        sums    = (float*)(ws + 1024);
    float*        counts  = (float*)(ws + 33792);
    unsigned int* binned  = (unsigned int*)(ws + 34816);
    float*        y       = (float*)(ws + 6457344);

    hipMemsetAsync(d_ws, 0, 34816, stream);   // gcursor + sums + counts

    k_front<<<PB + N_NODES * HIDDEN / 256, 256, 0, stream>>>(
        x, W1, y, ei, ei + N_EDGES, gcursor, binned);

    k_agg<<<NB, 1024, 0, stream>>>(binned, gcursor, y, batch,
                                   b1, W2, b2, sums, counts);

    k_out<<<1, 256, 0, stream>>>(sums, counts, Wc, bc, out);
}